// Round 3
// baseline (312.146 us; speedup 1.0000x reference)
//
#include <hip/hip_runtime.h>

// AttentionSampling: out[b,s,:] = q[b,s,:] + sum_f dot(LN(q)[b,s,:], LN(k)[b,4s+f,:]) * LN(v)[b,4s+f,:]
// B=4, Sq=2048, Skv=8192, D=1024, fp32.
//
// R3: latency-bound fix. R2 held 112 regs of load payload in a 68-VGPR budget ->
// compiler serialized loads into tiny batches with vmcnt waits -> ~1 load in
// flight per wave -> 2.8 TB/s latency ceiling. Now: k rows stream through an
// explicit 2-deep register double-buffer (compiler emits vmcnt(4)-style waits,
// 4+ loads always outstanding), per-element k work is 6 FMAs against persistent
// qw/w/b, all 27 wave-reductions batched after the k loop, and the 16 v loads
// issue behind a fence so their latency hides under the reduction chain.
// One wave per output row; reductions are pure-VALU DPP; zero LDS, zero barriers.

constexpr int D     = 1024;
constexpr int BLOCK = 256;           // 4 independent waves per block
constexpr float EPS = 1e-5f;

template<int CTRL>
__device__ __forceinline__ float dpp_add(float x) {
    int xi = __builtin_bit_cast(int, x);
    int yi = __builtin_amdgcn_update_dpp(0, xi, CTRL, 0xF, 0xF, true);
    return x + __builtin_bit_cast(float, yi);
}

// Full wave64 sum on the VALU pipe; result broadcast via readlane (SGPR).
__device__ __forceinline__ float wave_sum(float x) {
    x = dpp_add<0x111>(x);   // row_shr:1
    x = dpp_add<0x112>(x);   // row_shr:2
    x = dpp_add<0x114>(x);   // row_shr:4
    x = dpp_add<0x118>(x);   // row_shr:8
    x = dpp_add<0x142>(x);   // row_bcast:15
    x = dpp_add<0x143>(x);   // row_bcast:31 -> lane 63 holds wave sum
    return __builtin_bit_cast(float, __builtin_amdgcn_readlane(__builtin_bit_cast(int, x), 63));
}

__global__ __launch_bounds__(BLOCK, 3) void attn_ds_kernel(
    const float* __restrict__ q,    // [B*Sq, D]
    const float* __restrict__ k,    // [B*Sq*4, D]
    const float* __restrict__ v,    // [B*Sq*4, D]
    const float* __restrict__ lw,   // [D]
    const float* __restrict__ lb,   // [D]
    float* __restrict__ out)        // [B*Sq, D]
{
    const int lane = threadIdx.x & 63;
    const int wid  = threadIdx.x >> 6;
    const long row = (long)blockIdx.x * 4 + wid;   // 0..8191
    const int off0 = lane * 4;

    const float* qp = q + row * D;
    const float* kp = k + row * (4L * D);
    const float* vp = v + row * (4L * D);

    // ---- burst 1: w, b, q, k-row0 (16 coalesced dwordx4, 64 payload regs) ----
    float4 wv[4], bv[4], qv[4], kbuf[2][4];
#pragma unroll
    for (int c = 0; c < 4; c++) {
        const int e = c * 256 + off0;
        wv[c] = *(const float4*)(lw + e);
        bv[c] = *(const float4*)(lb + e);
        qv[c] = *(const float4*)(qp + e);
        kbuf[0][c] = *(const float4*)(kp + e);
    }

    // ---- q-phase per-lane partials (k0 still in flight behind this) ----
    float4 qw[4];
    float Sq = 0, Sqq = 0, Sqw2 = 0, Sqwb = 0, Sw2 = 0, Swb = 0, Sbb = 0;
#pragma unroll
    for (int c = 0; c < 4; c++) {
#define ACCQ(m) { \
        float qe = qv[c].m, we = wv[c].m, be = bv[c].m; \
        float qwe = qe * we; qw[c].m = qwe; \
        Sq += qe; Sqq = fmaf(qe, qe, Sqq); \
        Sqw2 = fmaf(qwe, we, Sqw2); Sqwb = fmaf(qwe, be, Sqwb); \
        Sw2 = fmaf(we, we, Sw2); Swb = fmaf(we, be, Swb); Sbb = fmaf(be, be, Sbb); }
        ACCQ(x) ACCQ(y) ACCQ(z) ACCQ(w)
#undef ACCQ
    }

    // ---- k loop: 2-deep register double-buffer, 4 loads always in flight ----
    float Sk[4], Skk[4], Skw2[4], Skwb[4], Sqk[4];
#pragma unroll
    for (int f = 0; f < 4; f++) {
        if (f < 3) {
#pragma unroll
            for (int c = 0; c < 4; c++)
                kbuf[(f + 1) & 1][c] = *(const float4*)(kp + (f + 1) * D + c * 256 + off0);
        }
        float s0 = 0, s1 = 0, s2 = 0, s3 = 0, s4 = 0;
#pragma unroll
        for (int c = 0; c < 4; c++) {
#define ACCK(m) { \
            float ke = kbuf[f & 1][c].m, we = wv[c].m, be = bv[c].m; \
            float kwe = ke * we; \
            s0 += ke; s1 = fmaf(ke, ke, s1); \
            s2 = fmaf(kwe, we, s2); s3 = fmaf(kwe, be, s3); \
            s4 = fmaf(qw[c].m, kwe, s4); }
            ACCK(x) ACCK(y) ACCK(z) ACCK(w)
#undef ACCK
        }
        Sk[f] = s0; Skk[f] = s1; Skw2[f] = s2; Skwb[f] = s3; Sqk[f] = s4;
    }

    // ---- issue all v loads now; their latency hides under the reductions ----
    asm volatile("" ::: "memory");
    float4 vv[4][4];
#pragma unroll
    for (int f = 0; f < 4; f++)
#pragma unroll
        for (int c = 0; c < 4; c++)
            vv[f][c] = *(const float4*)(vp + f * D + c * 256 + off0);

    // ---- batched round 1: 27 independent DPP reductions ----
    Sq = wave_sum(Sq);     Sqq = wave_sum(Sqq);
    Sqw2 = wave_sum(Sqw2); Sqwb = wave_sum(Sqwb);
    Sw2 = wave_sum(Sw2);   Swb = wave_sum(Swb);   Sbb = wave_sum(Sbb);
#pragma unroll
    for (int f = 0; f < 4; f++) {
        Sk[f] = wave_sum(Sk[f]);     Skk[f] = wave_sum(Skk[f]);
        Skw2[f] = wave_sum(Skw2[f]); Skwb[f] = wave_sum(Skwb[f]);
        Sqk[f] = wave_sum(Sqk[f]);
    }

    // ---- dp[f] from reduced scalars (uniform math, overlaps v latency) ----
    const float invD = 1.0f / (float)D;
    const float mu_q = Sq * invD;
    const float rs_q = rsqrtf(fmaf(-mu_q, mu_q, Sqq * invD) + EPS);
    const float qwb_c = Sqwb - mu_q * Swb;
    float dp[4];
#pragma unroll
    for (int f = 0; f < 4; f++) {
        float mu_k = Sk[f] * invD;
        float rs_k = rsqrtf(fmaf(-mu_k, mu_k, Skk[f] * invD) + EPS);
        float cross = Sqk[f] - mu_q * Skw2[f] - mu_k * Sqw2 + mu_q * mu_k * Sw2;
        dp[f] = rs_q * rs_k * cross + rs_q * qwb_c + rs_k * (Skwb[f] - mu_k * Swb) + Sbb;
    }

    // ---- v stats + round 2 (8 DPP reductions) ----
    float Sv[4], Svv[4];
#pragma unroll
    for (int f = 0; f < 4; f++) {
        float s0 = 0, s1 = 0;
#pragma unroll
        for (int c = 0; c < 4; c++) {
#define ACCV(m) { float ve = vv[f][c].m; s0 += ve; s1 = fmaf(ve, ve, s1); }
            ACCV(x) ACCV(y) ACCV(z) ACCV(w)
#undef ACCV
        }
        Sv[f] = wave_sum(s0); Svv[f] = wave_sum(s1);
    }

    // ---- epilogue: out = q + sum_f dp[f] * LN(v_f) ----
    float4 acc[4];
#pragma unroll
    for (int c = 0; c < 4; c++) acc[c] = qv[c];
#pragma unroll
    for (int f = 0; f < 4; f++) {
        float mu_v = Sv[f] * invD;
        float rs_v = rsqrtf(fmaf(-mu_v, mu_v, Svv[f] * invD) + EPS);
        float av = rs_v, cv = -mu_v * rs_v;
        float dpf = dp[f];
#pragma unroll
        for (int c = 0; c < 4; c++) {
#define ACCO(m) { \
            float t = fmaf(av, vv[f][c].m, cv); \
            float vn = fmaf(t, wv[c].m, bv[c].m); \
            acc[c].m = fmaf(dpf, vn, acc[c].m); }
            ACCO(x) ACCO(y) ACCO(z) ACCO(w)
#undef ACCO
        }
    }
#pragma unroll
    for (int c = 0; c < 4; c++)
        *(float4*)(out + row * D + c * 256 + off0) = acc[c];
}

extern "C" void kernel_launch(void* const* d_in, const int* in_sizes, int n_in,
                              void* d_out, int out_size, void* d_ws, size_t ws_size,
                              hipStream_t stream) {
    const float* q  = (const float*)d_in[0];
    const float* k  = (const float*)d_in[1];
    const float* v  = (const float*)d_in[2];
    const float* lw = (const float*)d_in[3];
    const float* lb = (const float*)d_in[4];
    float* out = (float*)d_out;

    const int rows = in_sizes[0] / D;          // B*Sq = 8192
    attn_ds_kernel<<<dim3(rows / 4), dim3(BLOCK), 0, stream>>>(q, k, v, lw, lb, out);
}

// Round 4
// 306.519 us; speedup vs baseline: 1.0184x; 1.0184x over previous
//
#include <hip/hip_runtime.h>

// AttentionSampling: out[b,s,:] = q[b,s,:] + sum_f dot(LN(q)[b,s,:], LN(k)[b,4s+f,:]) * LN(v)[b,4s+f,:]
// B=4, Sq=2048, Skv=8192, D=1024, fp32.
//
// R4: the R1-R3 plateau (117us) was per-wave load serialization: at 68 VGPRs the
// compiler sinks every global load to its use with a vmcnt wait -> ~1 outstanding
// load/wave -> ~2.8 TB/s latency ceiling. Fix: stage k,v (32 KB/row) into LDS via
// __builtin_amdgcn_global_load_lds (width 16) -- fire-and-forget, ZERO dest VGPRs,
// so all 32 staging requests per block are in flight at once. One block per row,
// q/w/b as 3 direct loads, one __syncthreads() drain, compute from LDS with pure-
// VALU DPP wave reductions + tiny LDS cross-wave combine.

constexpr int D     = 1024;
constexpr int BLOCK = 256;
constexpr int NW    = BLOCK / 64;
constexpr float EPS = 1e-5f;

#define GLOBAL_AS const __attribute__((address_space(1))) void*
#define LDS_AS __attribute__((address_space(3))) void*

template<int CTRL>
__device__ __forceinline__ float dpp_add(float x) {
    int xi = __builtin_bit_cast(int, x);
    int yi = __builtin_amdgcn_update_dpp(0, xi, CTRL, 0xF, 0xF, true);
    return x + __builtin_bit_cast(float, yi);
}

// Full wave64 sum on the VALU pipe; broadcast via readlane (SGPR).
__device__ __forceinline__ float wave_sum(float x) {
    x = dpp_add<0x111>(x);   // row_shr:1
    x = dpp_add<0x112>(x);   // row_shr:2
    x = dpp_add<0x114>(x);   // row_shr:4
    x = dpp_add<0x118>(x);   // row_shr:8
    x = dpp_add<0x142>(x);   // row_bcast:15
    x = dpp_add<0x143>(x);   // row_bcast:31 -> lane 63 holds wave sum
    return __builtin_bit_cast(float, __builtin_amdgcn_readlane(__builtin_bit_cast(int, x), 63));
}

// Block-wide sum of N per-thread values, broadcast to all threads.
template <int N>
__device__ __forceinline__ void block_reduce(float* vals, float* s_buf,
                                             int lane, int wid) {
#pragma unroll
    for (int i = 0; i < N; i++) {
        float x = wave_sum(vals[i]);
        if (lane == 0) s_buf[wid * N + i] = x;
    }
    __syncthreads();
#pragma unroll
    for (int i = 0; i < N; i++) {
        float t = 0.f;
#pragma unroll
        for (int w = 0; w < NW; w++) t += s_buf[w * N + i];
        vals[i] = t;
    }
    __syncthreads();
}

__global__ __launch_bounds__(BLOCK) void attn_ds_kernel(
    const float* __restrict__ q,    // [B*Sq, D]
    const float* __restrict__ k,    // [B*Sq*4, D]
    const float* __restrict__ v,    // [B*Sq*4, D]
    const float* __restrict__ lw,   // [D]
    const float* __restrict__ lb,   // [D]
    float* __restrict__ out)        // [B*Sq, D]
{
    __shared__ float kv_lds[8 * D];      // [0..4095]=k rows 0..3, [4096..8191]=v rows
    __shared__ float s_buf[NW * 18];

    const long row  = blockIdx.x;        // 0..8191
    const int  tid  = threadIdx.x;
    const int  lane = tid & 63;
    const int  wid  = tid >> 6;
    const int  d0   = tid * 4;           // this thread's 4 floats within D

    // ---- direct loads FIRST (so later waits on them don't drain staging) ----
    const float4 qv = *(const float4*)(q + row * D + d0);
    const float4 wv = *(const float4*)(lw + d0);
    const float4 bv = *(const float4*)(lb + d0);

    // ---- async k,v staging: 32 x 1KB chunks, fire-and-forget, no dest VGPRs ----
    // chunk c: c<16 -> k, c>=16 -> v; within group: row f=(c&15)/4, quarter j=(c&15)%4.
    // LDS dest is wave-uniform base; HW scatters lane i to base + i*16B.
    const float* kbase = k + row * (4L * D);
    const float* vbase = v + row * (4L * D);
#pragma unroll
    for (int i = 0; i < 8; i++) {
        const int c = wid + i * NW;                       // 8 chunks per wave
        const float* src = (c < 16 ? kbase : vbase) + (long)(c & 15) * 256 + lane * 4;
        float* dst = kv_lds + c * 256;                    // uniform per wave-instr
        __builtin_amdgcn_global_load_lds((GLOBAL_AS)src, (LDS_AS)dst, 16, 0, 0);
    }

    __syncthreads();   // compiler emits s_waitcnt vmcnt(0) here: staging + q/w/b done

    // ---- phase 1: sum & sumsq for q row, 4 k rows, 4 v rows (18 values) ----
    float red[18];
    red[0] = qv.x + qv.y + qv.z + qv.w;
    red[1] = qv.x * qv.x + qv.y * qv.y + qv.z * qv.z + qv.w * qv.w;
    float4 kv4[4], vv4[4];
#pragma unroll
    for (int f = 0; f < 4; f++) {
        kv4[f] = *(const float4*)(kv_lds + f * D + d0);
        vv4[f] = *(const float4*)(kv_lds + (4 + f) * D + d0);
        red[2 + 2 * f]  = kv4[f].x + kv4[f].y + kv4[f].z + kv4[f].w;
        red[3 + 2 * f]  = kv4[f].x * kv4[f].x + kv4[f].y * kv4[f].y
                        + kv4[f].z * kv4[f].z + kv4[f].w * kv4[f].w;
        red[10 + 2 * f] = vv4[f].x + vv4[f].y + vv4[f].z + vv4[f].w;
        red[11 + 2 * f] = vv4[f].x * vv4[f].x + vv4[f].y * vv4[f].y
                        + vv4[f].z * vv4[f].z + vv4[f].w * vv4[f].w;
    }
    block_reduce<18>(red, s_buf, lane, wid);

    const float invD = 1.0f / (float)D;
    const float mu_q = red[0] * invD;
    const float rs_q = rsqrtf(fmaf(-mu_q, mu_q, red[1] * invD) + EPS);
    float mu_k[4], rs_k[4], mu_v[4], rs_v[4];
#pragma unroll
    for (int f = 0; f < 4; f++) {
        mu_k[f] = red[2 + 2 * f] * invD;
        rs_k[f] = rsqrtf(fmaf(-mu_k[f], mu_k[f], red[3 + 2 * f] * invD) + EPS);
        mu_v[f] = red[10 + 2 * f] * invD;
        rs_v[f] = rsqrtf(fmaf(-mu_v[f], mu_v[f], red[11 + 2 * f] * invD) + EPS);
    }

    // ---- phase 2: dot(qn, kn_f) ----
    float4 qn;
    qn.x = fmaf((qv.x - mu_q) * rs_q, wv.x, bv.x);
    qn.y = fmaf((qv.y - mu_q) * rs_q, wv.y, bv.y);
    qn.z = fmaf((qv.z - mu_q) * rs_q, wv.z, bv.z);
    qn.w = fmaf((qv.w - mu_q) * rs_q, wv.w, bv.w);
    float dp[4];
#pragma unroll
    for (int f = 0; f < 4; f++) {
        float4 kn;
        kn.x = fmaf((kv4[f].x - mu_k[f]) * rs_k[f], wv.x, bv.x);
        kn.y = fmaf((kv4[f].y - mu_k[f]) * rs_k[f], wv.y, bv.y);
        kn.z = fmaf((kv4[f].z - mu_k[f]) * rs_k[f], wv.z, bv.z);
        kn.w = fmaf((kv4[f].w - mu_k[f]) * rs_k[f], wv.w, bv.w);
        dp[f] = qn.x * kn.x + qn.y * kn.y + qn.z * kn.z + qn.w * kn.w;
    }
    block_reduce<4>(dp, s_buf, lane, wid);

    // ---- epilogue: out = q + sum_f dp[f] * LN(v_f) ----
    float4 acc = qv;
#pragma unroll
    for (int f = 0; f < 4; f++) {
        const float av = rs_v[f], cv = -mu_v[f] * rs_v[f], dpf = dp[f];
#define ACCO(m) { \
        float t  = fmaf(av, vv4[f].m, cv); \
        float vn = fmaf(t, wv.m, bv.m); \
        acc.m = fmaf(dpf, vn, acc.m); }
        ACCO(x) ACCO(y) ACCO(z) ACCO(w)
#undef ACCO
    }
    *(float4*)(out + row * D + d0) = acc;
}

extern "C" void kernel_launch(void* const* d_in, const int* in_sizes, int n_in,
                              void* d_out, int out_size, void* d_ws, size_t ws_size,
                              hipStream_t stream) {
    const float* q  = (const float*)d_in[0];
    const float* k  = (const float*)d_in[1];
    const float* v  = (const float*)d_in[2];
    const float* lw = (const float*)d_in[3];
    const float* lb = (const float*)d_in[4];
    float* out = (float*)d_out;

    const int rows = in_sizes[0] / D;  // B*Sq = 8192
    attn_ds_kernel<<<dim3(rows), dim3(BLOCK), 0, stream>>>(q, k, v, lw, lb, out);
}